// Round 1
// baseline (181.761 us; speedup 1.0000x reference)
//
#include <hip/hip_runtime.h>
#include <hip/hip_bf16.h>

// LUTLayerBasic: out[b] = sum_d W[d*16 + ch(b,d)], ch = 4 sign bits of gathered x.
// Strategy: one-hot bf16 GEMM via MFMA. A (one-hot) generated on the fly from a
// 16x16-identity LDS LUT; W pre-converted to bf16 and pre-permuted into
// MFMA-fragment-linear order so staging is linear global_load_lds(16B) and
// B-fragment reads are conflict-free ds_read_b128.
//
// Dims: B=2048, N_IN=2048, D=1024, A=4, O=2048, C=16, N_LUT=16384 (= K).

typedef __attribute__((ext_vector_type(8))) short short8;
typedef __attribute__((ext_vector_type(4))) float f32x4;

__device__ __forceinline__ bool anchors_is_i64(const int* a) {
  // anchors values are in [0, 2048): if stored as int64, the hi dword of each
  // of the first 32 entries is 0. For int32 data, odd entries all-zero is
  // astronomically unlikely. Only touches first 4096 dwords (safe either way).
  int v = 0;
#pragma unroll
  for (int i = 0; i < 32; ++i) v |= a[2 * i + 1];
  return v == 0;
}

__device__ __forceinline__ int ld_anchor(const int* a, int i, bool is64) {
  return is64 ? a[2 * i] : a[i];
}

__device__ __forceinline__ unsigned f2bf(float f) {  // RNE f32 -> bf16
  unsigned u = __float_as_uint(f);
  return ((u + 0x7fffu + ((u >> 16) & 1u)) >> 16) & 0xffffu;
}

// ---------------------------------------------------------------------------
// Kernel 1: packed channels. chp[t][b] = ch(b, 2t) | ch(b, 2t+1)<<8, t in [0,512)
// ---------------------------------------------------------------------------
__global__ __launch_bounds__(256) void k_channels(const float* __restrict__ x,
                                                  const int* __restrict__ anc,
                                                  unsigned short* __restrict__ chp) {
  const int b = blockIdx.x * 256 + threadIdx.x;  // gridDim.x = 8
  const int t = blockIdx.y;                      // [0, 512)
  const bool is64 = anchors_is_i64(anc);
  unsigned ch0 = 0, ch1 = 0;
#pragma unroll
  for (int i = 0; i < 4; ++i) {
    int a0 = ld_anchor(anc, (2 * t) * 4 + i, is64);
    int a1 = ld_anchor(anc, (2 * t + 1) * 4 + i, is64);
    ch0 |= (x[(size_t)b * 2048 + a0] > 0.0f ? 1u : 0u) << i;
    ch1 |= (x[(size_t)b * 2048 + a1] > 0.0f ? 1u : 0u) << i;
  }
  chp[(size_t)t * 2048 + b] = (unsigned short)(ch0 | (ch1 << 8));
}

// ---------------------------------------------------------------------------
// Kernel 2: W (f32 [16384][2048]) -> bf16 fragment-linear layout:
//   chunk index ((kt*128 + nc)*64 + l), 16 bytes each, holding
//   W[kt*32 + kmap(l>>4, j)][nc*16 + (l&15)] for j=0..7,
//   kmap(q,j) = q*4 + (j&3) + 16*(j>>2)  (same map used by the GEMM's A LUT).
// ---------------------------------------------------------------------------
__global__ __launch_bounds__(256) void k_wfrag(const float* __restrict__ W,
                                               uint4* __restrict__ wf) {
  const unsigned flat = blockIdx.x * 256 + threadIdx.x;  // [0, 4194304)
  const unsigned l = flat & 63u, nc = (flat >> 6) & 127u, kt = flat >> 13;
  const unsigned q = l >> 4, col = nc * 16 + (l & 15);
  unsigned hs[8];
#pragma unroll
  for (int j = 0; j < 8; ++j) {
    unsigned k = kt * 32 + q * 4 + (j & 3) + ((j >> 2) << 4);
    hs[j] = f2bf(W[(size_t)k * 2048 + col]);
  }
  uint4 o;
  o.x = hs[0] | (hs[1] << 16);
  o.y = hs[2] | (hs[3] << 16);
  o.z = hs[4] | (hs[5] << 16);
  o.w = hs[6] | (hs[7] << 16);
  wf[flat] = o;
}

// ---------------------------------------------------------------------------
// Kernel 3: one-hot GEMM. Tile 128x128, 4 waves (2x2), wave tile 64x64,
// BK=32 (one detector pair / step), split-K via blockIdx.z.
// ---------------------------------------------------------------------------
__global__ __launch_bounds__(256, 2) void k_gemm(const uint4* __restrict__ wf,
                                                 const unsigned short* __restrict__ chp,
                                                 float* __restrict__ outBase,
                                                 int nsteps, int kpCount) {
  __shared__ uint4 wb[2][512];                 // 2 x 8 KiB W tiles
  __shared__ unsigned short cb[2][128];        // 2 x 256 B channel tiles
  __shared__ __align__(8) unsigned short lut[320];  // 16 entries x 20 ushort (40 B stride)

  const int tid = threadIdx.x;
  const int lane = tid & 63;
  const int w = tid >> 6, wm = w >> 1, wn = w & 1;

  // Bijective XCD-aware remap: group all 16 mBlk's of one (nBlk, kp) W-panel
  // onto one XCD so the staged panel (2 MiB) stays L2-resident.
  unsigned f = blockIdx.x + gridDim.x * blockIdx.y + gridDim.x * gridDim.y * blockIdx.z;
  unsigned xcd = f & 7u, slot = f >> 3;
  unsigned pl = slot >> 4;            // [0, 2*KP)
  unsigned mBlk = slot & 15u;
  unsigned panel = xcd * (2u * (unsigned)kpCount) + pl;  // [0, 16*KP)
  unsigned nBlk = panel & 15u;
  unsigned kp = panel >> 4;

  const int k0 = (int)kp * nsteps;

  // Build identity LUT: lut entry c, halfword h: (h==c) ? bf16(1.0) : 0
  for (int i = tid; i < 320; i += 256) {
    int c = i / 20, h = i % 20;
    lut[i] = (h == c) ? (unsigned short)0x3F80 : (unsigned short)0;
  }

  f32x4 acc[4][4];
#pragma unroll
  for (int a = 0; a < 4; ++a)
#pragma unroll
    for (int b = 0; b < 4; ++b) acc[a][b] = f32x4{0.f, 0.f, 0.f, 0.f};

  const uint4* wsrc = wf + (size_t)k0 * 8192 + (size_t)nBlk * 512;
  const char* csrc = (const char*)chp + (size_t)k0 * 4096 + (size_t)mBlk * 256 + lane * 4;

  auto stageW = [&](int step, int buf) {
#pragma unroll
    for (int t2 = 0; t2 < 2; ++t2) {
      __builtin_amdgcn_global_load_lds(
          (const __attribute__((address_space(1))) void*)(wsrc + (size_t)step * 8192 + t2 * 256 + tid),
          (__attribute__((address_space(3))) void*)(&wb[buf][t2 * 256 + w * 64]),
          16, 0, 0);
    }
    if (w == 0) {
      __builtin_amdgcn_global_load_lds(
          (const __attribute__((address_space(1))) void*)(csrc + (size_t)step * 4096),
          (__attribute__((address_space(3))) void*)(&cb[buf][0]),
          4, 0, 0);
    }
  };

  stageW(0, 0);
  __syncthreads();

  const unsigned q2 = ((unsigned)(lane >> 4) & 3u) * 8u;  // byte offset of q-window in lut entry
  int cur = 0;
  for (int step = 0; step < nsteps; ++step) {
    if (step + 1 < nsteps) stageW(step + 1, cur ^ 1);

    const uint4* wbc = &wb[cur][0];
    const unsigned short* chb = &cb[cur][0];

    short8 bfrag[4];
#pragma unroll
    for (int nf = 0; nf < 4; ++nf)
      bfrag[nf] = *(const short8*)(wbc + (wn * 4 + nf) * 64 + lane);

#pragma unroll
    for (int mi = 0; mi < 4; ++mi) {
      unsigned pk = chb[wm * 64 + mi * 16 + (lane & 15)];
      unsigned c0 = pk & 0xffu, c1 = pk >> 8;
      const char* lb = (const char*)lut;
      uint2 lo = *(const uint2*)(lb + c0 * 40 + q2);  // d0 window (A slots 0..3)
      uint2 hi = *(const uint2*)(lb + c1 * 40 + q2);  // d1 window (A slots 4..7)
      union { short8 v; unsigned u[4]; } af;
      af.u[0] = lo.x; af.u[1] = lo.y; af.u[2] = hi.x; af.u[3] = hi.y;
#pragma unroll
      for (int nf = 0; nf < 4; ++nf)
        acc[mi][nf] = __builtin_amdgcn_mfma_f32_16x16x32_bf16(af.v, bfrag[nf], acc[mi][nf], 0, 0, 0);
    }
    __syncthreads();
    cur ^= 1;
  }

  float* o = outBase + (size_t)kp * 4194304ull;
  const int row0 = (int)mBlk * 128 + wm * 64;
  const int col0 = (int)nBlk * 128 + wn * 64;
  const int rsub = ((lane >> 4) & 3) * 4;
  const int csub = lane & 15;
#pragma unroll
  for (int mi = 0; mi < 4; ++mi)
#pragma unroll
    for (int nf = 0; nf < 4; ++nf) {
      int r = row0 + mi * 16 + rsub;
      int c = col0 + nf * 16 + csub;
#pragma unroll
      for (int j = 0; j < 4; ++j)
        o[(size_t)(r + j) * 2048 + c] = acc[mi][nf][j];
    }
}

// ---------------------------------------------------------------------------
// Kernel 4: split-K reduce
// ---------------------------------------------------------------------------
__global__ __launch_bounds__(256) void k_reduce(const float* __restrict__ parts,
                                                float* __restrict__ out, int kp) {
  size_t i = ((size_t)blockIdx.x * 256 + threadIdx.x) * 4;
  f32x4 s = {0.f, 0.f, 0.f, 0.f};
  for (int p = 0; p < kp; ++p) s += *(const f32x4*)(parts + (size_t)p * 4194304ull + i);
  *(f32x4*)(out + i) = s;
}

// ---------------------------------------------------------------------------
// Fallback (ws too small): direct gather row-sum, one block per sample.
// ---------------------------------------------------------------------------
__global__ __launch_bounds__(256) void k_direct(const float* __restrict__ x,
                                                const int* __restrict__ anc,
                                                const float* __restrict__ W,
                                                float* __restrict__ out) {
  __shared__ unsigned rowoff[1024];
  const int b = blockIdx.x;
  const bool is64 = anchors_is_i64(anc);
  for (int d = threadIdx.x; d < 1024; d += 256) {
    unsigned ch = 0;
#pragma unroll
    for (int i = 0; i < 4; ++i) {
      int a = ld_anchor(anc, d * 4 + i, is64);
      ch |= (x[(size_t)b * 2048 + a] > 0.0f ? 1u : 0u) << i;
    }
    rowoff[d] = (unsigned)(d * 16 + ch) * 2048u;
  }
  __syncthreads();
  f32x4 a0 = {0.f, 0.f, 0.f, 0.f}, a1 = {0.f, 0.f, 0.f, 0.f};
  const int o0 = threadIdx.x * 4, o1 = 1024 + threadIdx.x * 4;
  for (int d = 0; d < 1024; ++d) {
    unsigned ro = rowoff[d];
    a0 += *(const f32x4*)(W + ro + o0);
    a1 += *(const f32x4*)(W + ro + o1);
  }
  *(f32x4*)(out + (size_t)b * 2048 + o0) = a0;
  *(f32x4*)(out + (size_t)b * 2048 + o1) = a1;
}

// ---------------------------------------------------------------------------
extern "C" void kernel_launch(void* const* d_in, const int* in_sizes, int n_in,
                              void* d_out, int out_size, void* d_ws, size_t ws_size,
                              hipStream_t stream) {
  const float* x = (const float*)d_in[0];
  const int* anc = (const int*)d_in[1];
  const float* W = (const float*)d_in[2];
  float* out = (float*)d_out;

  const size_t CHP_BYTES = 2ull * 1024 * 1024;    // 512 x 2048 u16
  const size_t WF_BYTES = 64ull * 1024 * 1024;    // 4M x 16 B
  const size_t BASE = CHP_BYTES + WF_BYTES;       // 66 MiB
  const size_t PART = 16ull * 1024 * 1024;        // one K-partial of C (f32)

  int KP = 0;
  if (ws_size >= BASE + 4 * PART) KP = 4;
  else if (ws_size >= BASE + 2 * PART) KP = 2;
  else if (ws_size >= BASE) KP = 1;

  if (KP == 0) {  // scratch too small for the GEMM plan
    k_direct<<<2048, 256, 0, stream>>>(x, anc, W, out);
    return;
  }

  unsigned short* chp = (unsigned short*)d_ws;
  uint4* wf = (uint4*)((char*)d_ws + CHP_BYTES);
  float* parts = (float*)((char*)d_ws + BASE);

  k_channels<<<dim3(8, 512), 256, 0, stream>>>(x, anc, chp);
  k_wfrag<<<16384, 256, 0, stream>>>(W, wf);

  int nsteps = 512 / KP;
  float* gout = (KP == 1) ? out : parts;
  k_gemm<<<dim3(16, 16, KP), 256, 0, stream>>>(wf, chp, gout, nsteps, KP);
  if (KP > 1) k_reduce<<<4096, 256, 0, stream>>>(parts, out, KP);
}